// Round 1
// baseline (365.832 us; speedup 1.0000x reference)
//
#include <hip/hip_runtime.h>

// SemanticRenderer: out[r, c] = sum_{i: ray_indices[i]==r} weights[i] * semantics[i, c]
// semantics: [N, 32] f32, weights: [N] f32, ray_indices: [N] int (SORTED), out: [R, 32] f32
//
// One wave (64 lanes) per ray. Segment bounds via binary search (indices sorted).
// lane = 8*g + q: g in [0,8) = sample subgroup, q in [0,8) = float4 class quad.
// Per iteration a wave reads 8 rows x 128B = 1KiB coalesced.

__global__ __launch_bounds__(256) void SemanticRenderer_70205535421052_kernel(
    const float4* __restrict__ sem4,   // [N*8] (N rows of 8 float4)
    const float*  __restrict__ w,      // [N]
    const int*    __restrict__ ridx,   // [N] sorted ray ids
    float4*       __restrict__ out4,   // [R*8]
    int N, int R)
{
    const int wave = threadIdx.x >> 6;
    const int lane = threadIdx.x & 63;
    const int q    = lane & 7;         // class quad (classes 4q..4q+3)
    const int g    = lane >> 3;        // sample subgroup 0..7
    const int r    = blockIdx.x * 4 + wave;
    if (r >= R) return;

    // lower_bound(r): first i with ridx[i] >= r
    int lo = 0, hi = N;
    while (lo < hi) {
        int mid = (lo + hi) >> 1;
        if (ridx[mid] < r) lo = mid + 1; else hi = mid;
    }
    const int start = lo;
    // lower_bound(r+1), starting from `start`
    hi = N;
    while (lo < hi) {
        int mid = (lo + hi) >> 1;
        if (ridx[mid] <= r) lo = mid + 1; else hi = mid;
    }
    const int end = lo;

    float4 acc; acc.x = 0.f; acc.y = 0.f; acc.z = 0.f; acc.w = 0.f;
    for (int s = start + g; s < end; s += 8) {
        const float ws = w[s];                       // broadcast within 8-lane group
        const float4 v = sem4[(size_t)s * 8 + q];    // 16B/lane, coalesced
        acc.x += ws * v.x;
        acc.y += ws * v.y;
        acc.z += ws * v.z;
        acc.w += ws * v.w;
    }

    // reduce across the 8 sample subgroups (lane bits 3,4,5) — wave is 64 lanes
    #pragma unroll
    for (int m = 8; m < 64; m <<= 1) {
        acc.x += __shfl_xor(acc.x, m, 64);
        acc.y += __shfl_xor(acc.y, m, 64);
        acc.z += __shfl_xor(acc.z, m, 64);
        acc.w += __shfl_xor(acc.w, m, 64);
    }

    if (g == 0) out4[(size_t)r * 8 + q] = acc;       // 128B row per ray
}

extern "C" void kernel_launch(void* const* d_in, const int* in_sizes, int n_in,
                              void* d_out, int out_size, void* d_ws, size_t ws_size,
                              hipStream_t stream) {
    const float4* sem4 = (const float4*)d_in[0];
    const float*  w    = (const float*)d_in[1];
    const int*    ridx = (const int*)d_in[2];
    float4*       out4 = (float4*)d_out;

    const int N = in_sizes[1];        // number of samples (weights is [N])
    const int R = out_size / 32;      // number of rays (out is [R,32])

    const int blocks = (R + 3) / 4;   // 4 rays (waves) per 256-thread block
    SemanticRenderer_70205535421052_kernel<<<blocks, 256, 0, stream>>>(
        sem4, w, ridx, out4, N, R);
}

// Round 2
// 128.846 us; speedup vs baseline: 2.8393x; 2.8393x over previous
//
#include <hip/hip_runtime.h>

// SemanticRenderer: out[r, c] = sum_{i: ray_indices[i]==r} weights[i] * semantics[i, c]
// semantics: [N, 32] f32, weights: [N] f32, ray_indices: [N] int32 (SORTED), out: [R, 32] f32
//
// Pass 1 (bounds): streaming scan of ridx; at each run boundary write
//   start[ray]=i, end[ray]=i+1 (unique writer per ray -> plain stores, deterministic).
// Pass 2 (render): one wave per ray; lane = 8*g + q; wave reads 8 rows x 128B
//   = 1 KiB coalesced per iteration. No binary search: just start[r]/end[r].

__global__ __launch_bounds__(256) void sr_bounds_kernel(
    const int* __restrict__ ridx, int* __restrict__ seg_start,
    int* __restrict__ seg_end, int N)
{
    const int stride = gridDim.x * blockDim.x;
    for (int i = blockIdx.x * blockDim.x + threadIdx.x; i < N; i += stride) {
        const int r = ridx[i];
        const int prev = (i == 0) ? -1 : ridx[i - 1];
        if (r != prev) seg_start[r] = i;
        const int next = (i == N - 1) ? -1 : ridx[i + 1];
        if (r != next) seg_end[r] = i + 1;
    }
}

__global__ __launch_bounds__(256) void SemanticRenderer_70205535421052_kernel(
    const float4* __restrict__ sem4,      // [N*8] (N rows of 8 float4)
    const float*  __restrict__ w,         // [N]
    const int*    __restrict__ seg_start, // [R] (-1 if ray empty)
    const int*    __restrict__ seg_end,   // [R]
    float4*       __restrict__ out4,      // [R*8]
    int R)
{
    const int wave = threadIdx.x >> 6;
    const int lane = threadIdx.x & 63;
    const int q    = lane & 7;            // class quad (classes 4q..4q+3)
    const int g    = lane >> 3;           // sample subgroup 0..7
    const int r    = blockIdx.x * 4 + wave;
    if (r >= R) return;

    const int start = seg_start[r];

    float4 acc; acc.x = 0.f; acc.y = 0.f; acc.z = 0.f; acc.w = 0.f;
    if (start >= 0) {
        const int end = seg_end[r];
        for (int s = start + g; s < end; s += 8) {
            const float  ws = w[s];                     // one 32B region per wave/iter
            const float4 v  = sem4[(size_t)s * 8 + q];  // 16B/lane, coalesced
            acc.x += ws * v.x;
            acc.y += ws * v.y;
            acc.z += ws * v.z;
            acc.w += ws * v.w;
        }
        // reduce across the 8 sample subgroups (lane bits 3,4,5); wave = 64 lanes
        #pragma unroll
        for (int m = 8; m < 64; m <<= 1) {
            acc.x += __shfl_xor(acc.x, m, 64);
            acc.y += __shfl_xor(acc.y, m, 64);
            acc.z += __shfl_xor(acc.z, m, 64);
            acc.w += __shfl_xor(acc.w, m, 64);
        }
    }
    if (g == 0) out4[(size_t)r * 8 + q] = acc;          // 128B row; zeros for empty rays
}

extern "C" void kernel_launch(void* const* d_in, const int* in_sizes, int n_in,
                              void* d_out, int out_size, void* d_ws, size_t ws_size,
                              hipStream_t stream) {
    const float4* sem4 = (const float4*)d_in[0];
    const float*  w    = (const float*)d_in[1];
    const int*    ridx = (const int*)d_in[2];
    float4*       out4 = (float4*)d_out;

    const int N = in_sizes[1];        // number of samples (weights is [N])
    const int R = out_size / 32;      // number of rays (out is [R,32])

    int* seg_start = (int*)d_ws;      // [R]
    int* seg_end   = seg_start + R;   // [R]

    // init seg_start to -1 (0xFF bytes); seg_end needs no init (only read when start>=0)
    hipMemsetAsync(seg_start, 0xFF, (size_t)R * sizeof(int), stream);

    sr_bounds_kernel<<<2048, 256, 0, stream>>>(ridx, seg_start, seg_end, N);

    const int blocks = (R + 3) / 4;   // 4 rays (waves) per 256-thread block
    SemanticRenderer_70205535421052_kernel<<<blocks, 256, 0, stream>>>(
        sem4, w, seg_start, seg_end, out4, R);
}

// Round 3
// 113.006 us; speedup vs baseline: 3.2373x; 1.1402x over previous
//
#include <hip/hip_runtime.h>

// SemanticRenderer: out[r, c] = sum_{i: ray_indices[i]==r} weights[i] * semantics[i, c]
// semantics: [N, 32] f32, weights: [N] f32, ray_indices: [N] int32 (SORTED), out: [R, 32] f32
//
// Pass 0: memset seg[] (int2 per ray) to 0 -> empty rays have start==end==0.
// Pass 1 (bounds): int4-vectorized scan of ridx; run boundaries write
//   seg[ray].x = start, seg[ray].y = end (unique writer per component).
// Pass 2 (render): one wave per ray; lane = 8*g + q; wave reads 8 rows x 128B
//   = 1 KiB coalesced per iter, 2-deep software pipeline (2 independent loads/iter).

__global__ __launch_bounds__(256) void sr_bounds_kernel(
    const int* __restrict__ ridx, int2* __restrict__ seg, int N)
{
    const int t  = blockIdx.x * blockDim.x + threadIdx.x;
    const int i4 = t * 4;
    if (i4 >= N) return;

    if (i4 + 4 <= N) {
        const int4 v = *reinterpret_cast<const int4*>(ridx + i4);
        const int prev = (i4 == 0) ? -1 : ridx[i4 - 1];
        const int tail = (i4 + 4 < N) ? ridx[i4 + 4] : -2;   // -2 matches no ray id
        if (v.x != prev) { seg[v.x].x = i4;     if (prev >= 0) seg[prev].y = i4; }
        if (v.y != v.x)  { seg[v.y].x = i4 + 1; seg[v.x].y = i4 + 1; }
        if (v.z != v.y)  { seg[v.z].x = i4 + 2; seg[v.y].y = i4 + 2; }
        if (v.w != v.z)  { seg[v.w].x = i4 + 3; seg[v.z].y = i4 + 3; }
        if (v.w != tail) { seg[v.w].y = i4 + 4; }
    } else {
        // scalar tail (N % 4 != 0)
        for (int i = i4; i < N; ++i) {
            const int r    = ridx[i];
            const int prev = (i == 0) ? -1 : ridx[i - 1];
            const int next = (i == N - 1) ? -2 : ridx[i + 1];
            if (r != prev) seg[r].x = i;
            if (r != next) seg[r].y = i + 1;
        }
    }
}

__global__ __launch_bounds__(256) void SemanticRenderer_70205535421052_kernel(
    const float4* __restrict__ sem4,   // [N*8] (N rows of 8 float4)
    const float*  __restrict__ w,      // [N]
    const int2*   __restrict__ seg,    // [R] (start, end); start==end for empty
    float4*       __restrict__ out4,   // [R*8]
    int R)
{
    const int wave = threadIdx.x >> 6;
    const int lane = threadIdx.x & 63;
    const int q    = lane & 7;         // class quad (classes 4q..4q+3)
    const int g    = lane >> 3;        // sample subgroup 0..7
    const int r    = blockIdx.x * 4 + wave;
    if (r >= R) return;

    const int2 se  = seg[r];           // one 8B load per lane (broadcast)
    const int  end = se.y;
    int s = se.x + g;

    float4 acc; acc.x = 0.f; acc.y = 0.f; acc.z = 0.f; acc.w = 0.f;

    // 2-deep pipeline: two independent 1 KiB wave-loads in flight per iteration
    for (; s + 8 < end; s += 16) {
        const float  w0 = w[s];
        const float  w1 = w[s + 8];
        const float4 v0 = sem4[(size_t)s * 8 + q];
        const float4 v1 = sem4[(size_t)(s + 8) * 8 + q];
        acc.x += w0 * v0.x; acc.y += w0 * v0.y; acc.z += w0 * v0.z; acc.w += w0 * v0.w;
        acc.x += w1 * v1.x; acc.y += w1 * v1.y; acc.z += w1 * v1.z; acc.w += w1 * v1.w;
    }
    if (s < end) {
        const float  w0 = w[s];
        const float4 v0 = sem4[(size_t)s * 8 + q];
        acc.x += w0 * v0.x; acc.y += w0 * v0.y; acc.z += w0 * v0.z; acc.w += w0 * v0.w;
    }

    // reduce across the 8 sample subgroups (lane bits 3,4,5); wave = 64 lanes
    #pragma unroll
    for (int m = 8; m < 64; m <<= 1) {
        acc.x += __shfl_xor(acc.x, m, 64);
        acc.y += __shfl_xor(acc.y, m, 64);
        acc.z += __shfl_xor(acc.z, m, 64);
        acc.w += __shfl_xor(acc.w, m, 64);
    }

    if (g == 0) out4[(size_t)r * 8 + q] = acc;   // 128B row; zeros for empty rays
}

extern "C" void kernel_launch(void* const* d_in, const int* in_sizes, int n_in,
                              void* d_out, int out_size, void* d_ws, size_t ws_size,
                              hipStream_t stream) {
    const float4* sem4 = (const float4*)d_in[0];
    const float*  w    = (const float*)d_in[1];
    const int*    ridx = (const int*)d_in[2];
    float4*       out4 = (float4*)d_out;

    const int N = in_sizes[1];        // number of samples (weights is [N])
    const int R = out_size / 32;      // number of rays (out is [R,32])

    int2* seg = (int2*)d_ws;          // [R] (start, end)

    // start==end==0 for rays never written (empty) -> loop skipped -> zeros stored
    hipMemsetAsync(seg, 0, (size_t)R * sizeof(int2), stream);

    const int bthreads = (N + 3) / 4;
    sr_bounds_kernel<<<(bthreads + 255) / 256, 256, 0, stream>>>(ridx, seg, N);

    const int blocks = (R + 3) / 4;   // 4 rays (waves) per 256-thread block
    SemanticRenderer_70205535421052_kernel<<<blocks, 256, 0, stream>>>(
        sem4, w, seg, out4, R);
}

// Round 4
// 108.407 us; speedup vs baseline: 3.3746x; 1.0424x over previous
//
#include <hip/hip_runtime.h>

// SemanticRenderer: out[r, c] = sum_{i: ray_indices[i]==r} weights[i] * semantics[i, c]
// semantics: [N, 32] f32, weights: [N] f32, ray_indices: [N] int32 (SORTED), out: [R, 32] f32
//
// Pass 0: memset seg[] (int2 per ray) to 0 -> empty rays have start==end==0.
// Pass 1 (bounds): int4-vectorized scan of ridx; run boundaries write
//   seg[ray] = (start, end) (unique writer per component).
// Pass 2 (render): one wave per ray; lane = 8*g + q; wave reads 8 rows x 128B
//   = 1 KiB coalesced per load; 4-deep software pipeline (4 independent loads
//   in flight -> covers the modal 32-sample segment in one batch).
// Nontemporal loads on the zero-reuse sem/w streams; nontemporal store for out.

typedef float  f32x4 __attribute__((ext_vector_type(4)));

__global__ __launch_bounds__(256) void sr_bounds_kernel(
    const int* __restrict__ ridx, int2* __restrict__ seg, int N)
{
    const int t  = blockIdx.x * blockDim.x + threadIdx.x;
    const int i4 = t * 4;
    if (i4 >= N) return;

    if (i4 + 4 <= N) {
        const int4 v = *reinterpret_cast<const int4*>(ridx + i4);
        const int prev = (i4 == 0) ? -1 : ridx[i4 - 1];
        const int tail = (i4 + 4 < N) ? ridx[i4 + 4] : -2;   // -2 matches no ray id
        if (v.x != prev) { seg[v.x].x = i4;     if (prev >= 0) seg[prev].y = i4; }
        if (v.y != v.x)  { seg[v.y].x = i4 + 1; seg[v.x].y = i4 + 1; }
        if (v.z != v.y)  { seg[v.z].x = i4 + 2; seg[v.y].y = i4 + 2; }
        if (v.w != v.z)  { seg[v.w].x = i4 + 3; seg[v.z].y = i4 + 3; }
        if (v.w != tail) { seg[v.w].y = i4 + 4; }
    } else {
        for (int i = i4; i < N; ++i) {
            const int r    = ridx[i];
            const int prev = (i == 0) ? -1 : ridx[i - 1];
            const int next = (i == N - 1) ? -2 : ridx[i + 1];
            if (r != prev) seg[r].x = i;
            if (r != next) seg[r].y = i + 1;
        }
    }
}

__global__ __launch_bounds__(256) void SemanticRenderer_70205535421052_kernel(
    const f32x4* __restrict__ sem4,    // [N*8] (N rows of 8 float4)
    const float* __restrict__ w,       // [N]
    const int2*  __restrict__ seg,     // [R] (start, end); start==end for empty
    f32x4*       __restrict__ out4,    // [R*8]
    int R)
{
    const int wave = threadIdx.x >> 6;
    const int lane = threadIdx.x & 63;
    const int q    = lane & 7;         // class quad (classes 4q..4q+3)
    const int g    = lane >> 3;        // sample subgroup 0..7
    const int r    = blockIdx.x * 4 + wave;
    if (r >= R) return;

    const int2 se  = seg[r];           // one 8B broadcast load per wave
    const int  end = se.y;
    int s = se.x + g;

    f32x4 acc = (f32x4)0.f;

    // 4-deep pipeline: four independent 1 KiB wave-loads in flight
    for (; s + 24 < end; s += 32) {
        const float w0 = __builtin_nontemporal_load(w + s);
        const float w1 = __builtin_nontemporal_load(w + s + 8);
        const float w2 = __builtin_nontemporal_load(w + s + 16);
        const float w3 = __builtin_nontemporal_load(w + s + 24);
        const f32x4 v0 = __builtin_nontemporal_load(sem4 + (size_t)s * 8 + q);
        const f32x4 v1 = __builtin_nontemporal_load(sem4 + (size_t)(s + 8)  * 8 + q);
        const f32x4 v2 = __builtin_nontemporal_load(sem4 + (size_t)(s + 16) * 8 + q);
        const f32x4 v3 = __builtin_nontemporal_load(sem4 + (size_t)(s + 24) * 8 + q);
        acc += w0 * v0;
        acc += w1 * v1;
        acc += w2 * v2;
        acc += w3 * v3;
    }
    // 2-deep remainder
    for (; s + 8 < end; s += 16) {
        const float w0 = __builtin_nontemporal_load(w + s);
        const float w1 = __builtin_nontemporal_load(w + s + 8);
        const f32x4 v0 = __builtin_nontemporal_load(sem4 + (size_t)s * 8 + q);
        const f32x4 v1 = __builtin_nontemporal_load(sem4 + (size_t)(s + 8) * 8 + q);
        acc += w0 * v0;
        acc += w1 * v1;
    }
    if (s < end) {
        const float w0 = __builtin_nontemporal_load(w + s);
        const f32x4 v0 = __builtin_nontemporal_load(sem4 + (size_t)s * 8 + q);
        acc += w0 * v0;
    }

    // reduce across the 8 sample subgroups (lane bits 3,4,5); wave = 64 lanes
    #pragma unroll
    for (int m = 8; m < 64; m <<= 1) {
        acc.x += __shfl_xor(acc.x, m, 64);
        acc.y += __shfl_xor(acc.y, m, 64);
        acc.z += __shfl_xor(acc.z, m, 64);
        acc.w += __shfl_xor(acc.w, m, 64);
    }

    if (g == 0) __builtin_nontemporal_store(acc, out4 + (size_t)r * 8 + q);
}

extern "C" void kernel_launch(void* const* d_in, const int* in_sizes, int n_in,
                              void* d_out, int out_size, void* d_ws, size_t ws_size,
                              hipStream_t stream) {
    const f32x4* sem4 = (const f32x4*)d_in[0];
    const float* w    = (const float*)d_in[1];
    const int*   ridx = (const int*)d_in[2];
    f32x4*       out4 = (f32x4*)d_out;

    const int N = in_sizes[1];        // number of samples (weights is [N])
    const int R = out_size / 32;      // number of rays (out is [R,32])

    int2* seg = (int2*)d_ws;          // [R] (start, end)

    // start==end==0 for rays never written (empty) -> loop skipped -> zeros stored
    hipMemsetAsync(seg, 0, (size_t)R * sizeof(int2), stream);

    const int bthreads = (N + 3) / 4;
    sr_bounds_kernel<<<(bthreads + 255) / 256, 256, 0, stream>>>(ridx, seg, N);

    const int blocks = (R + 3) / 4;   // 4 rays (waves) per 256-thread block
    SemanticRenderer_70205535421052_kernel<<<blocks, 256, 0, stream>>>(
        sem4, w, seg, out4, R);
}